// Round 4
// baseline (856.420 us; speedup 1.0000x reference)
//
#include <hip/hip_runtime.h>
#include <hip/hip_bf16.h>
#include <stdint.h>

#define NE 131072

typedef __attribute__((ext_vector_type(8))) short bf16x8;
typedef __attribute__((ext_vector_type(4))) float f32x4;

__device__ __forceinline__ unsigned short f2bf(float f) {
  unsigned u = __float_as_uint(f);
  u += 0x7FFF + ((u >> 16) & 1);   // round-to-nearest-even
  return (unsigned short)(u >> 16);
}
__device__ __forceinline__ float bf2f(unsigned short h) {
  return __uint_as_float((unsigned)h << 16);
}

__device__ __forceinline__ void gload_lds16(const void* g, void* l) {
  __builtin_amdgcn_global_load_lds(
      (const __attribute__((address_space(1))) unsigned*)g,
      (__attribute__((address_space(3))) unsigned*)l, 16, 0, 0);
}

// Fused weight prep: 12 (job,z) units on blockIdx.y, LDS-tiled transpose+cvt.
// dst[n][k] = bf16(src[k][n])
__global__ void weight_prep(const float* __restrict__ W0, const float* __restrict__ W1,
                            const float* __restrict__ W2, const float* __restrict__ SW0,
                            const float* __restrict__ SW1, const float* __restrict__ SW2,
                            unsigned short* W0t, unsigned short* W1t,
                            unsigned short* W2t, unsigned short* SW0t,
                            unsigned short* SW1t, unsigned short* SW2b) {
  __shared__ float tile[32][33];
  const int u = blockIdx.y;
  const float* src; unsigned short* dst; int K, Nc;
  if (u == 0)      { src = W0;  dst = W0t;  K = 64;  Nc = 512; }
  else if (u == 1) { src = W1;  dst = W1t;  K = 512; Nc = 512; }
  else if (u == 2) { src = W2;  dst = W2t;  K = 512; Nc = 512; }
  else if (u < 6)  { int p = u - 3; src = SW0 + (long)p * 512 * 512; dst = SW0t + (long)p * 512 * 512; K = 512; Nc = 512; }
  else if (u < 9)  { int p = u - 6; src = SW1 + (long)p * 512 * 256; dst = SW1t + (long)p * 256 * 512; K = 512; Nc = 256; }
  else             { int p = u - 9; src = SW2 + (long)p * 256;       dst = SW2b + (long)p * 256;       K = 256; Nc = 1; }
  const int tkn = K >> 5;
  const int tk = blockIdx.x % tkn, tn = blockIdx.x / tkn;
  if (tn >= ((Nc + 31) >> 5)) return;
  const int k0 = tk * 32, n0 = tn * 32;
  const int tx = threadIdx.x & 31, ty = threadIdx.x >> 5;
  if (n0 + tx < Nc)
#pragma unroll
    for (int j = 0; j < 4; ++j)
      tile[ty * 4 + j][tx] = src[(long)(k0 + ty * 4 + j) * Nc + n0 + tx];
  __syncthreads();
#pragma unroll
  for (int j = 0; j < 4; ++j) {
    int n = n0 + ty * 4 + j;
    if (n < Nc) dst[(long)n * K + k0 + tx] = f2bf(tile[tx][ty * 4 + j]);
  }
}

__global__ void relu_cvt_x(const float4* __restrict__ x,
                           ushort4* __restrict__ xb) {
  int i = blockIdx.x * blockDim.x + threadIdx.x;
  float4 v = x[i];
  ushort4 o;
  o.x = f2bf(fmaxf(v.x, 0.f));
  o.y = f2bf(fmaxf(v.y, 0.f));
  o.z = f2bf(fmaxf(v.z, 0.f));
  o.w = f2bf(fmaxf(v.w, 0.f));
  xb[i] = o;
}

// C[128rows x 512] = A[rows x K] * Bt[512 x K]^T + bias. Full-width BN=512:
// A read exactly once. 8 waves (2M x 4N), BK=32, m97-style 2-barrier loop.
__global__ __launch_bounds__(512) void gemmW(
    const unsigned short* __restrict__ A,
    const unsigned short* __restrict__ Bt,
    const float* __restrict__ bias,
    float* __restrict__ outF,
    unsigned short* __restrict__ outA,
    int K) {
  __shared__ unsigned short As[128 * 32];   // 8 KB
  __shared__ unsigned short Bs[512 * 32];   // 32 KB
  const int tid = threadIdx.x;
  const int wave = tid >> 6, lane = tid & 63;
  const int wm = wave >> 2, wn = wave & 3;
  const int lr = lane & 15, lh = lane >> 4;
  const long row0 = (long)blockIdx.x * 128;

  f32x4 acc[4][8];
#pragma unroll
  for (int m = 0; m < 4; ++m)
#pragma unroll
    for (int n = 0; n < 8; ++n) acc[m][n] = (f32x4){0.f, 0.f, 0.f, 0.f};

  const int nk = K >> 5;
  for (int kt = 0; kt < nk; ++kt) {
    const int k0 = kt << 5;
    gload_lds16(A + (row0 + (tid >> 2)) * K + k0 + (tid & 3) * 8,
                &As[wave * 64 * 8]);
#pragma unroll
    for (int i = 0; i < 4; ++i) {
      int c = i * 512 + tid;
      gload_lds16(Bt + (long)(c >> 2) * K + k0 + (c & 3) * 8,
                  &Bs[(i * 512 + wave * 64) * 8]);
    }
    __syncthreads();
    bf16x8 a[4], b[8];
#pragma unroll
    for (int m = 0; m < 4; ++m)
      a[m] = *(const bf16x8*)&As[(wm * 64 + m * 16 + lr) * 32 + lh * 8];
#pragma unroll
    for (int n = 0; n < 8; ++n)
      b[n] = *(const bf16x8*)&Bs[(wn * 128 + n * 16 + lr) * 32 + lh * 8];
#pragma unroll
    for (int m = 0; m < 4; ++m)
#pragma unroll
      for (int n = 0; n < 8; ++n)
        acc[m][n] =
            __builtin_amdgcn_mfma_f32_16x16x32_bf16(a[m], b[n], acc[m][n], 0, 0, 0);
    __syncthreads();
  }

  float bv[8];
#pragma unroll
  for (int n = 0; n < 8; ++n) bv[n] = bias[wn * 128 + n * 16 + lr];
#pragma unroll
  for (int m = 0; m < 4; ++m) {
#pragma unroll
    for (int r = 0; r < 4; ++r) {
      long e = row0 + wm * 64 + m * 16 + lh * 4 + r;
#pragma unroll
      for (int n = 0; n < 8; ++n) {
        int oc = wn * 128 + n * 16 + lr;
        float v = acc[m][n][r] + bv[n];
        if (outF) outF[e * 512 + oc] = v;
        if (outA) outA[e * 512 + oc] = f2bf(fmaxf(v, 0.f));
      }
    }
  }
}

// Fused subnet kernel. blockIdx.z = pair p; 128 events per block.
// Phase 1 (operand-swapped SW0): h0^T[512h x 128e] = SW0t(h,d) x repr^T(d,e).
//   C-frag gives 4 consecutive h per lane -> one ds_write_b64 into row-major
//   swizzled h0[e][512h] LDS tile (bias+relu applied in-register).
// Phase 2 (SW1): h1 = h0 x SW1t^T, A-frags from swizzled LDS, B from L2.
// Epilogue: fused 256->1 head + sigmoid/clip/ratio/mask.
__global__ __launch_bounds__(512) void subnet_fused(
    const unsigned short* __restrict__ bufR,   // [rows][512] bf16 relu(repr)
    const unsigned short* __restrict__ SW0t,   // [P][512h][512d]
    const float* __restrict__ Sb0,             // [P][512]
    const unsigned short* __restrict__ SW1t,   // [P][256][512]
    const float* __restrict__ Sb1,             // [P][256]
    const unsigned short* __restrict__ W2b,    // [P][256]
    const float* __restrict__ Sb2,             // [P]
    const int* __restrict__ y, const int* __restrict__ pairs,
    int r0,
    float* __restrict__ outR, float* __restrict__ outS,
    float* __restrict__ outM) {
  __shared__ unsigned short h0[65536];   // 128 KB; first 40 KB doubles as staging
  __shared__ float lbias[512];
  __shared__ float part[4][128];
  const int p = blockIdx.z;
  const int tid = threadIdx.x, wave = tid >> 6, lane = tid & 63;
  const int lr = lane & 15, lh = lane >> 4;
  const long erow0 = (long)blockIdx.x * 128;
  const unsigned short* Wt = SW0t + (long)p * 512 * 512;
  const unsigned short* Rb = bufR + erow0 * 512;

  lbias[tid] = Sb0[p * 512 + tid];

  // ---- phase 1: waves 4(hidden) x 2(events) ----
  const int wm4 = wave >> 1, wn2 = wave & 1;
  f32x4 acc[8][4];
#pragma unroll
  for (int m = 0; m < 8; ++m)
#pragma unroll
    for (int n = 0; n < 4; ++n) acc[m][n] = (f32x4){0.f, 0.f, 0.f, 0.f};

  unsigned short* Ast = h0;            // [512][32] = 32 KB
  unsigned short* Bst = h0 + 16384;    // [128][32] = 8 KB

  for (int kt = 0; kt < 16; ++kt) {
    const int k0 = kt << 5;
#pragma unroll
    for (int i = 0; i < 4; ++i) {
      int c = i * 512 + tid;
      gload_lds16(Wt + (long)(c >> 2) * 512 + k0 + (c & 3) * 8,
                  &Ast[(i * 512 + wave * 64) * 8]);
    }
    gload_lds16(Rb + (long)(tid >> 2) * 512 + k0 + (tid & 3) * 8,
                &Bst[wave * 64 * 8]);
    __syncthreads();
    bf16x8 a[8], b[4];
#pragma unroll
    for (int m = 0; m < 8; ++m)
      a[m] = *(const bf16x8*)&Ast[(wm4 * 128 + m * 16 + lr) * 32 + lh * 8];
#pragma unroll
    for (int n = 0; n < 4; ++n)
      b[n] = *(const bf16x8*)&Bst[(wn2 * 64 + n * 16 + lr) * 32 + lh * 8];
#pragma unroll
    for (int m = 0; m < 8; ++m)
#pragma unroll
      for (int n = 0; n < 4; ++n)
        acc[m][n] =
            __builtin_amdgcn_mfma_f32_16x16x32_bf16(a[m], b[n], acc[m][n], 0, 0, 0);
    __syncthreads();
  }

  // pack relu(acc+bias) -> h0[e][h] (bf16, XOR-swizzled), 8B per fragment
#pragma unroll
  for (int m = 0; m < 8; ++m) {
    const int h4 = wm4 * 128 + m * 16 + lh * 4;
    const f32x4 bv = *(const f32x4*)&lbias[h4];
#pragma unroll
    for (int n = 0; n < 4; ++n) {
      const int e = wn2 * 64 + n * 16 + lr;
      uint2 v;
      unsigned short p0 = f2bf(fmaxf(acc[m][n][0] + bv[0], 0.f));
      unsigned short p1 = f2bf(fmaxf(acc[m][n][1] + bv[1], 0.f));
      unsigned short p2 = f2bf(fmaxf(acc[m][n][2] + bv[2], 0.f));
      unsigned short p3 = f2bf(fmaxf(acc[m][n][3] + bv[3], 0.f));
      v.x = (unsigned)p0 | ((unsigned)p1 << 16);
      v.y = (unsigned)p2 | ((unsigned)p3 << 16);
      const int byte = (e * 1024 + h4 * 2) ^ ((e & 7) << 4);
      *reinterpret_cast<uint2*>(reinterpret_cast<char*>(h0) + byte) = v;
    }
  }
  __syncthreads();

  // ---- phase 2: waves 2(events) x 4(outcols); no barriers in K-loop ----
  const int wm2 = wave >> 2, wn4 = wave & 3;
  const unsigned short* W1p = SW1t + (long)p * 256 * 512;
  f32x4 acc2[4][4];
#pragma unroll
  for (int m = 0; m < 4; ++m)
#pragma unroll
    for (int n = 0; n < 4; ++n) acc2[m][n] = (f32x4){0.f, 0.f, 0.f, 0.f};

  for (int kt = 0; kt < 16; ++kt) {
    const int k = kt * 32 + lh * 8;
    bf16x8 a2[4], b2[4];
#pragma unroll
    for (int m = 0; m < 4; ++m) {
      const int e = wm2 * 64 + m * 16 + lr;
      const int byte = (e * 1024 + k * 2) ^ ((e & 7) << 4);
      a2[m] = *reinterpret_cast<const bf16x8*>(
          reinterpret_cast<const char*>(h0) + byte);
    }
#pragma unroll
    for (int n = 0; n < 4; ++n) {
      const int oc = wn4 * 64 + n * 16 + lr;
      b2[n] = *(const bf16x8*)&W1p[(long)oc * 512 + k];
    }
#pragma unroll
    for (int m = 0; m < 4; ++m)
#pragma unroll
      for (int n = 0; n < 4; ++n)
        acc2[m][n] =
            __builtin_amdgcn_mfma_f32_16x16x32_bf16(a2[m], b2[n], acc2[m][n], 0, 0, 0);
  }

  // ---- fused head ----
  float b1v[4], w2v[4];
#pragma unroll
  for (int n = 0; n < 4; ++n) {
    const int oc = wn4 * 64 + n * 16 + lr;
    b1v[n] = Sb1[p * 256 + oc];
    w2v[n] = bf2f(W2b[p * 256 + oc]);
  }
#pragma unroll
  for (int m = 0; m < 4; ++m) {
#pragma unroll
    for (int r = 0; r < 4; ++r) {
      float s = 0.f;
#pragma unroll
      for (int n = 0; n < 4; ++n)
        s += fmaxf(acc2[m][n][r] + b1v[n], 0.f) * w2v[n];
#pragma unroll
      for (int off = 1; off < 16; off <<= 1) s += __shfl_xor(s, off);
      if (lr == 0) part[wn4][wm2 * 64 + m * 16 + lh * 4 + r] = s;
    }
  }
  __syncthreads();
  if (tid < 128) {
    float logit = part[0][tid] + part[1][tid] + part[2][tid] + part[3][tid] +
                  Sb2[p];
    float s = 1.f / (1.f + expf(-logit));
    s = fmaxf(s, 1e-9f);
    float rr = (1.f - s) / s;
    long n = r0 + erow0 + tid;
    int yv = y[n];
    float mf = (yv == pairs[p * 2] || yv == pairs[p * 2 + 1]) ? 1.f : 0.f;
    outR[(long)p * NE + n] = rr * mf;
    outS[(long)p * NE + n] = s * mf;
    outM[(long)p * NE + n] = mf;
  }
}

extern "C" void kernel_launch(void* const* d_in, const int* in_sizes, int n_in,
                              void* d_out, int out_size, void* d_ws, size_t ws_size,
                              hipStream_t stream) {
  const float* x   = (const float*)d_in[0];
  const int*   y   = (const int*)d_in[1];
  const int*   prs = (const int*)d_in[2];
  const float* W0  = (const float*)d_in[3];
  const float* b0  = (const float*)d_in[4];
  const float* W1  = (const float*)d_in[5];
  const float* b1  = (const float*)d_in[6];
  const float* W2  = (const float*)d_in[7];
  const float* b2  = (const float*)d_in[8];
  const float* SW0 = (const float*)d_in[9];
  const float* Sb0 = (const float*)d_in[10];
  const float* SW1 = (const float*)d_in[11];
  const float* Sb1 = (const float*)d_in[12];
  const float* SW2 = (const float*)d_in[13];
  const float* Sb2 = (const float*)d_in[14];

  uint8_t* ws = (uint8_t*)d_ws;
  size_t off = 0;
  auto take = [&](size_t bytes) -> void* {
    void* ptr = ws + off;
    off = (off + bytes + 255) & ~(size_t)255;
    return ptr;
  };
  unsigned short* W0t  = (unsigned short*)take((size_t)64 * 512 * 2);
  unsigned short* W1t  = (unsigned short*)take((size_t)512 * 512 * 2);
  unsigned short* W2t  = (unsigned short*)take((size_t)512 * 512 * 2);
  unsigned short* SW0t = (unsigned short*)take((size_t)3 * 512 * 512 * 2);
  unsigned short* SW1t = (unsigned short*)take((size_t)3 * 256 * 512 * 2);
  unsigned short* SW2b = (unsigned short*)take((size_t)3 * 256 * 2);
  unsigned short* Xb   = (unsigned short*)take((size_t)NE * 64 * 2);
  size_t fixed = off;

  // chunk size gated on ws_size (deterministic): need fixed + 2*chunk*1024 B
  int chunk = 32768;
  if (ws_size >= fixed + (size_t)2 * 131072 * 1024 + 4096) chunk = 131072;
  else if (ws_size >= fixed + (size_t)2 * 65536 * 1024 + 4096) chunk = 65536;

  unsigned short* T0 = (unsigned short*)take((size_t)chunk * 512 * 2);
  unsigned short* T1 = (unsigned short*)take((size_t)chunk * 512 * 2);
  unsigned short* bufR = T0;  // alias: T0 dead once L2 runs (L2 reads T1)

  float* out   = (float*)d_out;
  float* outRe = out;
  float* outR  = out + (size_t)NE * 512;
  float* outS  = outR + (size_t)3 * NE;
  float* outM  = outS + (size_t)3 * NE;

  weight_prep<<<dim3(256, 12), 256, 0, stream>>>(W0, W1, W2, SW0, SW1, SW2,
                                                 W0t, W1t, W2t, SW0t, SW1t, SW2b);
  relu_cvt_x<<<dim3(NE * 64 / 4 / 256), 256, 0, stream>>>((const float4*)x,
                                                          (ushort4*)Xb);

  for (int r0 = 0; r0 < NE; r0 += chunk) {
    // trunk, full-width tiles (A read once per layer)
    gemmW<<<dim3(chunk / 128), 512, 0, stream>>>(
        Xb + (size_t)r0 * 64, W0t, b0, nullptr, T0, 64);
    gemmW<<<dim3(chunk / 128), 512, 0, stream>>>(T0, W1t, b1, nullptr, T1, 512);
    gemmW<<<dim3(chunk / 128), 512, 0, stream>>>(
        T1, W2t, b2, outRe + (size_t)r0 * 512, bufR, 512);
    // fused SW0+SW1+head, batched over pairs
    subnet_fused<<<dim3(chunk / 128, 1, 3), 512, 0, stream>>>(
        bufR, SW0t, Sb0, SW1t, Sb1, SW2b, Sb2, y, prs, r0, outR, outS, outM);
  }
}